// Round 2
// baseline (1083.989 us; speedup 1.0000x reference)
//
#include <hip/hip_runtime.h>
#include <math.h>

#define NEG -1e30f

constexpr int B  = 16;
constexpr int T  = 200;
constexpr int U  = 100;
constexpr int U1 = 101;   // U+1
constexpr int V  = 512;
constexpr int NDIAG = T + U1 - 1;  // 300 anti-diagonals

__device__ __forceinline__ float logaddexpf_(float a, float b) {
    float mx = fmaxf(a, b);
    float mn = fminf(a, b);
    return mx + log1pf(__expf(mn - mx));
}

// Kernel 1: one 64-lane wave per (b,t,u) row of 512 logits.
// Rows with t >= act_lens[b] or u > label_lens[b] cannot influence the loss:
// skip the 2KB read entirely and write NEG markers (saves ~34% of HBM traffic).
// Live rows: logsumexp + write blank_lp/emit_lp in DIAGONAL-major layout:
//   idx = b*NDIAG*U1 + (t+u)*U1 + u
__global__ void lse_extract_kernel(const float* __restrict__ acts,
                                   const int*   __restrict__ labels,
                                   const int*   __restrict__ act_lens,
                                   const int*   __restrict__ label_lens,
                                   float* __restrict__ blankD,
                                   float* __restrict__ emitD) {
    const int nrows = B * T * U1;
    int gid   = blockIdx.x * blockDim.x + threadIdx.x;
    int wave  = gid >> 6;
    int lane  = threadIdx.x & 63;
    int nwaves = (gridDim.x * blockDim.x) >> 6;
    // preload the 16 lens into lane registers; per-row broadcast via shfl (no mem op)
    int al_v = (lane < B) ? act_lens[lane]   : 0;
    int ll_v = (lane < B) ? label_lens[lane] : 0;
    for (int row = wave; row < nrows; row += nwaves) {
        int u  = row % U1;
        int bt = row / U1;
        int t  = bt % T;
        int b  = bt / T;
        int al = __shfl(al_v, b, 64);
        int ll = __shfl(ll_v, b, 64);
        size_t dpos = ((size_t)b * NDIAG + (t + u)) * U1 + u;
        if (t >= al || u > ll) {               // dead row: cannot reach (t_end,u_end)
            if (lane == 0) { blankD[dpos] = NEG; emitD[dpos] = NEG; }
            continue;
        }
        const float*  p  = acts + (size_t)row * V;
        const float4* p4 = (const float4*)p;
        float4 x0 = p4[lane * 2];
        float4 x1 = p4[lane * 2 + 1];
        float m = fmaxf(fmaxf(fmaxf(x0.x, x0.y), fmaxf(x0.z, x0.w)),
                        fmaxf(fmaxf(x1.x, x1.y), fmaxf(x1.z, x1.w)));
        #pragma unroll
        for (int off = 32; off; off >>= 1) m = fmaxf(m, __shfl_xor(m, off, 64));
        float s = __expf(x0.x - m) + __expf(x0.y - m) + __expf(x0.z - m) + __expf(x0.w - m)
                + __expf(x1.x - m) + __expf(x1.y - m) + __expf(x1.z - m) + __expf(x1.w - m);
        #pragma unroll
        for (int off = 32; off; off >>= 1) s += __shfl_xor(s, off, 64);
        float lse = m + __logf(s);
        if (lane == 0) {
            blankD[dpos] = x0.x - lse;          // x0.x == p[0] on lane 0 (blank logit)
            float e = NEG;
            if (u < ll) {                        // u == label_lens stays NEG (reference mask)
                int lab = labels[b * U + u];
                e = p[lab] - lse;                // L1/L2 hit — row was just streamed
            }
            emitD[dpos] = e;
        }
    }
}

// Kernel 2: diagonal-wavefront DP, ONE WAVE per batch element, no LDS, no barriers.
// Lane l owns u = l (A0) and u = l+64 (A1, valid l<=36). Previous diagonal lives in
// registers; u-1 neighbor via shfl_up; bl/em inputs prefetched 4 diagonals ahead in a
// statically-indexed register ring (unroll-by-4, trip count padded to 300 => no
// remainder loop => no scratch).
__global__ void __launch_bounds__(64) dp_kernel(const float* __restrict__ blankD,
                                                const float* __restrict__ emitD,
                                                const int*   __restrict__ act_lens,
                                                const int*   __restrict__ label_lens,
                                                float* __restrict__ costs) {
    int b = blockIdx.x;
    int l = threadIdx.x;          // 0..63
    const float* bl = blankD + (size_t)b * NDIAG * U1;
    const float* em = emitD  + (size_t)b * NDIAG * U1;
    int t_end = act_lens[b] - 1;
    int u_end = label_lens[b];
    int dF    = t_end + u_end;                       // final diagonal (<= 299)
    float blF = bl[(size_t)dF * U1 + u_end];         // blank_lp at (t_end, u_end)

    float A0 = (l == 0) ? 0.0f : NEG;                // alpha[0][0] = 0
    float A1 = NEG;

    constexpr int PF = 4;
    float pbl0[PF], pem0[PF], pbl1[PF], pem1[PF];
    #pragma unroll
    for (int s = 0; s < PF; ++s) {                   // preload diagonals 1..4
        int base = s * U1;                           // inputs for diag d live at (d-1)*U1
        pbl0[s] = bl[base + l];
        pem0[s] = (l >= 1)  ? em[base + l - 1]  : NEG;
        pbl1[s] = (l <= 36) ? bl[base + l + 64] : NEG;
        pem1[s] = (l <= 37) ? em[base + l + 63] : NEG;
    }

    #pragma unroll 4
    for (int d = 1; d <= 300; ++d) {                 // 300 = 75*4: exact unroll, d=300 inert
        int slot = (d - 1) & 3;                      // static after unroll
        float bl0 = pbl0[slot], em0 = pem0[slot];
        float bl1 = pbl1[slot], em1 = pem1[slot];

        // neighbor (u-1) values from the previous diagonal — pure register exchange
        float A0m1 = __shfl_up(A0, 1, 64);
        float A1m1 = __shfl_up(A1, 1, 64);
        float a63  = __shfl(A0, 63, 64);             // seam: u=64 needs prev alpha at u=63
        if (l == 0) A1m1 = a63;

        int t0 = d - l;
        int t1 = t0 - 64;

        float v0;
        if (l == 0)        v0 = A0 + bl0;                        // blank-only column
        else if (t0 == 0)  v0 = A0m1 + em0;                      // emit-only row (t=0)
        else               v0 = logaddexpf_(A0 + bl0, A0m1 + em0);
        if (t0 >= 0 && t0 < T) A0 = v0;

        float v1;
        if (t1 == 0)       v1 = A1m1 + em1;                      // t=0 row, u>=64
        else               v1 = logaddexpf_(A1 + bl1, A1m1 + em1);
        if (l <= 36 && t1 >= 0 && t1 < T) A1 = v1;

        if (d == dF) {                                // uniform scalar branch, fires once
            if (u_end < 64) { if (l == u_end)      costs[b] = -(A0 + blF); }
            else            { if (l == u_end - 64) costs[b] = -(A1 + blF); }
        }

        // refill this slot with diagonal d+PF (independent of the DP chain)
        if (d + PF <= 300) {
            int base = (d + PF - 1) * U1;
            pbl0[slot] = bl[base + l];
            pem0[slot] = (l >= 1)  ? em[base + l - 1]  : NEG;
            pbl1[slot] = (l <= 36) ? bl[base + l + 64] : NEG;
            pem1[slot] = (l <= 37) ? em[base + l + 63] : NEG;
        }
    }
}

// Kernel 3: mean of the 16 per-utterance costs.
__global__ void finalize_kernel(const float* __restrict__ costs, float* __restrict__ out) {
    int lane = threadIdx.x;
    float v = (lane < B) ? costs[lane] : 0.0f;
    #pragma unroll
    for (int off = 8; off; off >>= 1) v += __shfl_xor(v, off, 64);
    if (lane == 0) out[0] = v * (1.0f / (float)B);
}

extern "C" void kernel_launch(void* const* d_in, const int* in_sizes, int n_in,
                              void* d_out, int out_size, void* d_ws, size_t ws_size,
                              hipStream_t stream) {
    const float* acts       = (const float*)d_in[0];
    const int*   labels     = (const int*)d_in[1];
    const int*   act_lens   = (const int*)d_in[2];
    const int*   label_lens = (const int*)d_in[3];
    float* out = (float*)d_out;

    // Workspace layout (floats): blankD | emitD | costs  (~3.7 MB total)
    float* blankD = (float*)d_ws;
    float* emitD  = blankD + (size_t)B * NDIAG * U1;
    float* costs  = emitD  + (size_t)B * NDIAG * U1;

    lse_extract_kernel<<<4096, 256, 0, stream>>>(acts, labels, act_lens, label_lens, blankD, emitD);
    dp_kernel<<<B, 64, 0, stream>>>(blankD, emitD, act_lens, label_lens, costs);
    finalize_kernel<<<1, 64, 0, stream>>>(costs, out);
}

// Round 3
// 1056.495 us; speedup vs baseline: 1.0260x; 1.0260x over previous
//
#include <hip/hip_runtime.h>
#include <math.h>

#define NEG -1e30f

constexpr int B  = 16;
constexpr int T  = 200;
constexpr int U  = 100;
constexpr int U1 = 101;   // U+1
constexpr int V  = 512;
constexpr int NDIAG = T + U1 - 1;  // 300 anti-diagonals

__device__ __forceinline__ float logaddexpf_(float a, float b) {
    float mx = fmaxf(a, b);
    float mn = fminf(a, b);
    return mx + log1pf(__expf(mn - mx));
}

// Kernel 1: one 64-lane wave per (b,t,u) row of 512 logits.
// Rows with t >= act_lens[b] or u > label_lens[b] cannot influence the loss:
// skip the 2KB read entirely and write NEG markers (saves ~34% of HBM traffic).
// Live rows: logsumexp + write blank_lp/emit_lp in DIAGONAL-major layout:
//   idx = b*NDIAG*U1 + (t+u)*U1 + u
__global__ void lse_extract_kernel(const float* __restrict__ acts,
                                   const int*   __restrict__ labels,
                                   const int*   __restrict__ act_lens,
                                   const int*   __restrict__ label_lens,
                                   float* __restrict__ blankD,
                                   float* __restrict__ emitD) {
    const int nrows = B * T * U1;
    int gid   = blockIdx.x * blockDim.x + threadIdx.x;
    int wave  = gid >> 6;
    int lane  = threadIdx.x & 63;
    int nwaves = (gridDim.x * blockDim.x) >> 6;
    // preload the 16 lens into lane registers; per-row broadcast via shfl (no mem op)
    int al_v = (lane < B) ? act_lens[lane]   : 0;
    int ll_v = (lane < B) ? label_lens[lane] : 0;
    for (int row = wave; row < nrows; row += nwaves) {
        int u  = row % U1;
        int bt = row / U1;
        int t  = bt % T;
        int b  = bt / T;
        int al = __shfl(al_v, b, 64);
        int ll = __shfl(ll_v, b, 64);
        size_t dpos = ((size_t)b * NDIAG + (t + u)) * U1 + u;
        if (t >= al || u > ll) {               // dead row: cannot reach (t_end,u_end)
            if (lane == 0) { blankD[dpos] = NEG; emitD[dpos] = NEG; }
            continue;
        }
        const float*  p  = acts + (size_t)row * V;
        const float4* p4 = (const float4*)p;
        float4 x0 = p4[lane * 2];
        float4 x1 = p4[lane * 2 + 1];
        float m = fmaxf(fmaxf(fmaxf(x0.x, x0.y), fmaxf(x0.z, x0.w)),
                        fmaxf(fmaxf(x1.x, x1.y), fmaxf(x1.z, x1.w)));
        #pragma unroll
        for (int off = 32; off; off >>= 1) m = fmaxf(m, __shfl_xor(m, off, 64));
        float s = __expf(x0.x - m) + __expf(x0.y - m) + __expf(x0.z - m) + __expf(x0.w - m)
                + __expf(x1.x - m) + __expf(x1.y - m) + __expf(x1.z - m) + __expf(x1.w - m);
        #pragma unroll
        for (int off = 32; off; off >>= 1) s += __shfl_xor(s, off, 64);
        float lse = m + __logf(s);
        if (lane == 0) {
            blankD[dpos] = x0.x - lse;          // x0.x == p[0] on lane 0 (blank logit)
            float e = NEG;
            if (u < ll) {                        // u == label_lens stays NEG (reference mask)
                int lab = labels[b * U + u];
                e = p[lab] - lse;                // L1/L2 hit — row was just streamed
            }
            emitD[dpos] = e;
        }
    }
}

// Kernel 2: diagonal-wavefront DP, ONE WAVE per batch element, no LDS, no barriers.
// Lane l owns u = l (A0) and u = l+64 (A1, valid l<=36). Previous diagonal lives in
// registers; u-1 neighbor via shfl_up. The 4-deep input prefetch ring is HAND-UNROLLED
// into 16 NAMED scalars (no arrays at all) so no runtime indexing can ever reach
// scratch (rule #20). Loop = 75 iterations x 4 explicit phases covering d = 1..300
// exactly (d=300 is inert: all t0 >= T), so there is no remainder loop.
__global__ void __launch_bounds__(64) dp_kernel(const float* __restrict__ blankD,
                                                const float* __restrict__ emitD,
                                                const int*   __restrict__ act_lens,
                                                const int*   __restrict__ label_lens,
                                                float* __restrict__ costs) {
    int b = blockIdx.x;
    int l = threadIdx.x;          // 0..63
    const float* bl = blankD + (size_t)b * NDIAG * U1;
    const float* em = emitD  + (size_t)b * NDIAG * U1;
    int t_end = act_lens[b] - 1;
    int u_end = label_lens[b];
    int dF    = t_end + u_end;                       // final diagonal (<= 299)
    float blF = bl[(size_t)dF * U1 + u_end];         // blank_lp at (t_end, u_end)

    float A0 = (l == 0) ? 0.0f : NEG;                // alpha[0][0] = 0
    float A1 = NEG;

    const bool lo1 = (l >= 1);    // has a u-1 neighbor in the low half
    const bool hi0 = (l <= 36);   // owns u = l+64 (u <= 100)
    const bool hi1 = (l <= 37);   // may read em at u-1 = l+63 (<= 100)

    // Inputs for diagonal dd live at row (dd-1) of the diag-major arrays.
    // Slots beyond the geometric diagonal range hold poison (never written by lse);
    // every consumer is predicated by 0 <= t < T before any value is stored.
#define LOADS(S, dd)                                              \
    { int base_ = ((dd) - 1) * U1;                                \
      pbl0_##S = bl[base_ + l];                                   \
      pem0_##S = lo1 ? em[base_ + l - 1]  : NEG;                  \
      pbl1_##S = hi0 ? bl[base_ + l + 64] : NEG;                  \
      pem1_##S = hi1 ? em[base_ + l + 63] : NEG; }

    float pbl0_0, pem0_0, pbl1_0, pem1_0;
    float pbl0_1, pem0_1, pbl1_1, pem1_1;
    float pbl0_2, pem0_2, pbl1_2, pem1_2;
    float pbl0_3, pem0_3, pbl1_3, pem1_3;
    LOADS(0, 1) LOADS(1, 2) LOADS(2, 3) LOADS(3, 4)

#define STEP(S, dd)                                               \
    { float bl0 = pbl0_##S, em0 = pem0_##S;                       \
      float bl1 = pbl1_##S, em1 = pem1_##S;                       \
      float A0m1 = __shfl_up(A0, 1, 64);                          \
      float A1m1 = __shfl_up(A1, 1, 64);                          \
      float a63  = __shfl(A0, 63, 64);  /* seam: u=64 reads u=63 */\
      if (l == 0) A1m1 = a63;                                     \
      int t0 = (dd) - l;                                          \
      int t1 = t0 - 64;                                           \
      float v0;                                                   \
      if (l == 0)        v0 = A0 + bl0;          /* blank-only col */ \
      else if (t0 == 0)  v0 = A0m1 + em0;        /* emit-only row  */ \
      else               v0 = logaddexpf_(A0 + bl0, A0m1 + em0);  \
      if (t0 >= 0 && t0 < T) A0 = v0;                             \
      float v1;                                                   \
      if (t1 == 0)       v1 = A1m1 + em1;                         \
      else               v1 = logaddexpf_(A1 + bl1, A1m1 + em1);  \
      if (hi0 && t1 >= 0 && t1 < T) A1 = v1;                      \
      if ((dd) == dF) {                /* scalar compare, fires once */ \
          if (u_end < 64) { if (l == u_end)      costs[b] = -(A0 + blF); } \
          else            { if (l == u_end - 64) costs[b] = -(A1 + blF); } \
      }                                                           \
      if ((dd) + 4 <= NDIAG) LOADS(S, (dd) + 4) }

    for (int it = 0; it < 75; ++it) {
        int d = it * 4 + 1;
        STEP(0, d)
        STEP(1, d + 1)
        STEP(2, d + 2)
        STEP(3, d + 3)
    }
#undef STEP
#undef LOADS
}

// Kernel 3: mean of the 16 per-utterance costs.
__global__ void finalize_kernel(const float* __restrict__ costs, float* __restrict__ out) {
    int lane = threadIdx.x;
    float v = (lane < B) ? costs[lane] : 0.0f;
    #pragma unroll
    for (int off = 8; off; off >>= 1) v += __shfl_xor(v, off, 64);
    if (lane == 0) out[0] = v * (1.0f / (float)B);
}

extern "C" void kernel_launch(void* const* d_in, const int* in_sizes, int n_in,
                              void* d_out, int out_size, void* d_ws, size_t ws_size,
                              hipStream_t stream) {
    const float* acts       = (const float*)d_in[0];
    const int*   labels     = (const int*)d_in[1];
    const int*   act_lens   = (const int*)d_in[2];
    const int*   label_lens = (const int*)d_in[3];
    float* out = (float*)d_out;

    // Workspace layout (floats): blankD | emitD | costs  (~3.9 MB total)
    float* blankD = (float*)d_ws;
    float* emitD  = blankD + (size_t)B * NDIAG * U1;
    float* costs  = emitD  + (size_t)B * NDIAG * U1;

    lse_extract_kernel<<<4096, 256, 0, stream>>>(acts, labels, act_lens, label_lens, blankD, emitD);
    dp_kernel<<<B, 64, 0, stream>>>(blankD, emitD, act_lens, label_lens, costs);
    finalize_kernel<<<1, 64, 0, stream>>>(costs, out);
}